// Round 2
// baseline (277.804 us; speedup 1.0000x reference)
//
#include <hip/hip_runtime.h>
#include <cstdint>
#include <cstddef>

#define BB   32
#define NN   1024
#define FIN  128
#define FOUT 128

typedef __attribute__((ext_vector_type(8))) short bf16x8;
typedef __attribute__((ext_vector_type(4))) float f32x4;

__device__ __forceinline__ unsigned int f2bf(float f) {
    union { float f; unsigned int u; } v; v.f = f;
    unsigned int u = v.u;
    return (u + 0x7FFFu + ((u >> 16) & 1u)) >> 16;   // RNE fp32 -> bf16
}
__device__ __forceinline__ unsigned int pack2(float a, float b) {
    return f2bf(a) | (f2bf(b) << 16);
}

// ---------------------------------------------------------------------------
// Kernel 1: Yt[b][o][m] = sum_f node[b][m][f] * W[o][f]  (bf16, [B][FOUT][NN])
// (unchanged — measured ~3 us, not the target)
// ---------------------------------------------------------------------------
__global__ __launch_bounds__(256) void y_kernel(const float* __restrict__ node,
                                                const float* __restrict__ W,
                                                unsigned short* __restrict__ Yt) {
    __shared__ unsigned short Wlds[128 * 136];
    __shared__ unsigned short Nlds[64 * 136];

    const int tid = threadIdx.x;
    const int bid = blockIdx.x;
    const int b   = bid >> 4;
    const int m0  = (bid & 15) * 64;

    #pragma unroll
    for (int i = 0; i < 16; ++i) {
        const int idx = i * 256 + tid;
        const int row = idx >> 5;
        const int c   = (idx & 31) * 4;
        float4 v = ((const float4*)W)[idx];
        uint2 p; p.x = pack2(v.x, v.y); p.y = pack2(v.z, v.w);
        *(uint2*)&Wlds[row * 136 + c] = p;
    }
    {
        const float* base = node + ((size_t)b * NN + m0) * FIN;
        #pragma unroll
        for (int i = 0; i < 8; ++i) {
            const int idx = i * 256 + tid;
            const int row = idx >> 5;
            const int c   = (idx & 31) * 4;
            float4 v = *(const float4*)(base + row * FIN + c);
            uint2 p; p.x = pack2(v.x, v.y); p.y = pack2(v.z, v.w);
            *(uint2*)&Nlds[row * 136 + c] = p;
        }
    }
    __syncthreads();

    const int w = tid >> 6, lane = tid & 63;
    const int wo = w * 32;
    const int lcol = lane & 15, lk = (lane >> 4) * 8;

    f32x4 acc[2][4] = {};
    #pragma unroll
    for (int kc = 0; kc < 4; ++kc) {
        const int kof = kc * 32 + lk;
        bf16x8 a[2], bb[4];
        #pragma unroll
        for (int mi = 0; mi < 2; ++mi)
            a[mi] = *(const bf16x8*)&Wlds[(wo + mi*16 + lcol) * 136 + kof];
        #pragma unroll
        for (int ni = 0; ni < 4; ++ni)
            bb[ni] = *(const bf16x8*)&Nlds[(ni*16 + lcol) * 136 + kof];
        #pragma unroll
        for (int mi = 0; mi < 2; ++mi)
            #pragma unroll
            for (int ni = 0; ni < 4; ++ni)
                acc[mi][ni] = __builtin_amdgcn_mfma_f32_16x16x32_bf16(
                    a[mi], bb[ni], acc[mi][ni], 0, 0, 0);
    }
    __syncthreads();

    unsigned short* Ylds = Wlds;
    const int rq = (lane >> 4) * 4;
    #pragma unroll
    for (int mi = 0; mi < 2; ++mi)
        #pragma unroll
        for (int ni = 0; ni < 4; ++ni)
            #pragma unroll
            for (int r = 0; r < 4; ++r) {
                const int o = wo + mi * 16 + rq + r;
                const int m = ni * 16 + lcol;
                Ylds[o * 72 + m] = (unsigned short)f2bf(acc[mi][ni][r]);
            }
    __syncthreads();

    {
        const int oq = tid >> 3, c = (tid & 7) * 8;
        #pragma unroll
        for (int j = 0; j < 4; ++j) {
            const int o = oq + 32 * j;
            uint4 v = *(const uint4*)&Ylds[o * 72 + c];
            *(uint4*)(Yt + ((size_t)b * FOUT + o) * NN + m0 + c) = v;
        }
    }
}

// ---------------------------------------------------------------------------
// Kernel 2 v4: zero-LDS streaming MFMA, re-tiled for occupancy.
// Round-1 post-mortem: 512 blocks = 2 blocks/CU = 2 waves/SIMD -> latency-
// bound (Occupancy 21%, MfmaUtil 3%, VALUBusy 6%). Same inner loop, finer
// tiling: grid 1024 = 32 b x 32 row-tiles(32); block 256 = 4 waves in 2x2,
// each wave 16 rows x 64 cols (acc[4]). 4 blocks/CU -> 16 waves/CU (2x TLP).
// adj lines now read by 2 waves of the same block (concurrent -> 1 HBM
// fetch + L2 hit); B-read L2 traffic invariant (512 MB total).
// Fragment k-indices (kc*32 + q*8) byte-identical to the verified path.
// XCD-contiguous bid swizzle (1024 %% 8 == 0 -> bijective): 4 batches
// = 1 MB Yt per XCD L2.
// ---------------------------------------------------------------------------
__global__ __launch_bounds__(256, 4) void gcn_kernel(const float* __restrict__ adj,
                                                     const unsigned short* __restrict__ Yt,
                                                     const float* __restrict__ bias,
                                                     float* __restrict__ out) {
    const int tid  = threadIdx.x;
    const int lane = tid & 63;
    const int w    = tid >> 6;

    const int raw = blockIdx.x;
    const int bid = (raw & 7) * 128 + (raw >> 3);    // XCD-contiguous chunks
    const int b   = bid >> 5;
    const int n0  = (bid & 31) * 32;

    const int lcol = lane & 15, q = lane >> 4;
    const int wm = (w & 1) * 16;                     // row half  (0 / 16)
    const int wn = (w >> 1) * 64;                    // col half  (0 / 64)
    const int row  = n0 + wm + lcol;                 // this lane's adj/out row

    // A: adj[b][row][k], k = kc*32 + q*8  (two 16B loads per step)
    const float* aP = adj + ((size_t)b * NN + row) * NN + q * 8;
    // B: Yt[b][o][k], o = wn + ni*16 + lcol  (16B bf16x8 per step)
    const unsigned short* bP[4];
    #pragma unroll
    for (int ni = 0; ni < 4; ++ni)
        bP[ni] = Yt + ((size_t)b * FOUT + wn + ni * 16 + lcol) * NN + q * 8;

    f32x4 acc[4] = {};
    float rsum = 0.f;

    #pragma unroll 2
    for (int kc = 0; kc < 32; ++kc) {
        const float4 a0 = *(const float4*)(aP);
        const float4 a1 = *(const float4*)(aP + 4);
        aP += 32;
        rsum += ((a0.x + a0.y) + (a0.z + a0.w)) + ((a1.x + a1.y) + (a1.z + a1.w));
        uint4 pk;
        pk.x = pack2(a0.x, a0.y); pk.y = pack2(a0.z, a0.w);
        pk.z = pack2(a1.x, a1.y); pk.w = pack2(a1.z, a1.w);
        const bf16x8 a = *(const bf16x8*)&pk;
        #pragma unroll
        for (int ni = 0; ni < 4; ++ni) {
            const bf16x8 bb = *(const bf16x8*)bP[ni];
            bP[ni] += 32;
            acc[ni] = __builtin_amdgcn_mfma_f32_16x16x32_bf16(a, bb, acc[ni], 0, 0, 0);
        }
    }

    // full row sums: lanes sharing lcol hold disjoint k-quarters of row wm+lcol
    rsum += __shfl_xor(rsum, 16);
    rsum += __shfl_xor(rsum, 32);

    // D layout: col = lane&15 (o), row-in-tile = q*4 + r.
    // 1/rowsum for row wm+(rq+r): lane rq+r holds it (lcol = rq+r).
    const int rq = q * 4;
    float sc[4];
    #pragma unroll
    for (int r = 0; r < 4; ++r) sc[r] = 1.0f / __shfl(rsum, rq + r);

    float* outB = out + ((size_t)(b * NN + n0 + wm)) * FOUT;
    #pragma unroll
    for (int ni = 0; ni < 4; ++ni) {
        const float bc = bias[wn + ni * 16 + lcol];
        #pragma unroll
        for (int r = 0; r < 4; ++r) {
            float v = acc[ni][r] * sc[r] + bc;
            v = (v >= 0.f) ? v : 0.01f * v;
            outB[(size_t)(rq + r) * FOUT + wn + ni * 16 + lcol] = v;
        }
    }
}

extern "C" void kernel_launch(void* const* d_in, const int* in_sizes, int n_in,
                              void* d_out, int out_size, void* d_ws, size_t ws_size,
                              hipStream_t stream) {
    const float* node = (const float*)d_in[0];   // [32,1024,128]
    const float* adj  = (const float*)d_in[1];   // [32,1024,1024]
    const float* W    = (const float*)d_in[2];   // [128,128]
    const float* bias = (const float*)d_in[3];   // [128]
    float* out = (float*)d_out;                  // [32,1024,128] fp32
    unsigned short* Yt = (unsigned short*)d_ws;  // [32,128,1024] bf16 = 8 MiB

    hipLaunchKernelGGL(y_kernel,   dim3(512),  dim3(256), 0, stream, node, W, Yt);
    hipLaunchKernelGGL(gcn_kernel, dim3(1024), dim3(256), 0, stream, adj, Yt, bias, out);
}

// Round 3
// 234.936 us; speedup vs baseline: 1.1825x; 1.1825x over previous
//
#include <hip/hip_runtime.h>
#include <cstdint>
#include <cstddef>

#define BB   32
#define NN   1024
#define FIN  128
#define FOUT 128

typedef __attribute__((ext_vector_type(8))) short bf16x8;
typedef __attribute__((ext_vector_type(4))) float f32x4;

__device__ __forceinline__ unsigned int f2bf(float f) {
    union { float f; unsigned int u; } v; v.f = f;
    unsigned int u = v.u;
    return (u + 0x7FFFu + ((u >> 16) & 1u)) >> 16;   // RNE fp32 -> bf16
}
__device__ __forceinline__ unsigned int pack2(float a, float b) {
    return f2bf(a) | (f2bf(b) << 16);
}

// async global -> LDS DMA, 16 B per lane; LDS dst is wave-uniform base,
// HW scatters lane i to base + i*16 (m97/m104 semantics)
__device__ __forceinline__ void load_lds16(const void* g, void* l) {
    __builtin_amdgcn_global_load_lds(
        (const __attribute__((address_space(1))) unsigned int*)g,
        (__attribute__((address_space(3))) unsigned int*)l, 16, 0, 0);
}

// ---------------------------------------------------------------------------
// Kernel 1: Yt[b][o][m] = sum_f node[b][m][f] * W[o][f]  (bf16, [B][FOUT][NN])
// (unchanged — measured ~3 us, not the target)
// ---------------------------------------------------------------------------
__global__ __launch_bounds__(256) void y_kernel(const float* __restrict__ node,
                                                const float* __restrict__ W,
                                                unsigned short* __restrict__ Yt) {
    __shared__ unsigned short Wlds[128 * 136];
    __shared__ unsigned short Nlds[64 * 136];

    const int tid = threadIdx.x;
    const int bid = blockIdx.x;
    const int b   = bid >> 4;
    const int m0  = (bid & 15) * 64;

    #pragma unroll
    for (int i = 0; i < 16; ++i) {
        const int idx = i * 256 + tid;
        const int row = idx >> 5;
        const int c   = (idx & 31) * 4;
        float4 v = ((const float4*)W)[idx];
        uint2 p; p.x = pack2(v.x, v.y); p.y = pack2(v.z, v.w);
        *(uint2*)&Wlds[row * 136 + c] = p;
    }
    {
        const float* base = node + ((size_t)b * NN + m0) * FIN;
        #pragma unroll
        for (int i = 0; i < 8; ++i) {
            const int idx = i * 256 + tid;
            const int row = idx >> 5;
            const int c   = (idx & 31) * 4;
            float4 v = *(const float4*)(base + row * FIN + c);
            uint2 p; p.x = pack2(v.x, v.y); p.y = pack2(v.z, v.w);
            *(uint2*)&Nlds[row * 136 + c] = p;
        }
    }
    __syncthreads();

    const int w = tid >> 6, lane = tid & 63;
    const int wo = w * 32;
    const int lcol = lane & 15, lk = (lane >> 4) * 8;

    f32x4 acc[2][4] = {};
    #pragma unroll
    for (int kc = 0; kc < 4; ++kc) {
        const int kof = kc * 32 + lk;
        bf16x8 a[2], bb[4];
        #pragma unroll
        for (int mi = 0; mi < 2; ++mi)
            a[mi] = *(const bf16x8*)&Wlds[(wo + mi*16 + lcol) * 136 + kof];
        #pragma unroll
        for (int ni = 0; ni < 4; ++ni)
            bb[ni] = *(const bf16x8*)&Nlds[(ni*16 + lcol) * 136 + kof];
        #pragma unroll
        for (int mi = 0; mi < 2; ++mi)
            #pragma unroll
            for (int ni = 0; ni < 4; ++ni)
                acc[mi][ni] = __builtin_amdgcn_mfma_f32_16x16x32_bf16(
                    a[mi], bb[ni], acc[mi][ni], 0, 0, 0);
    }
    __syncthreads();

    unsigned short* Ylds = Wlds;
    const int rq = (lane >> 4) * 4;
    #pragma unroll
    for (int mi = 0; mi < 2; ++mi)
        #pragma unroll
        for (int ni = 0; ni < 4; ++ni)
            #pragma unroll
            for (int r = 0; r < 4; ++r) {
                const int o = wo + mi * 16 + rq + r;
                const int m = ni * 16 + lcol;
                Ylds[o * 72 + m] = (unsigned short)f2bf(acc[mi][ni][r]);
            }
    __syncthreads();

    {
        const int oq = tid >> 3, c = (tid & 7) * 8;
        #pragma unroll
        for (int j = 0; j < 4; ++j) {
            const int o = oq + 32 * j;
            uint4 v = *(const uint4*)&Ylds[o * 72 + c];
            *(uint4*)(Yt + ((size_t)b * FOUT + o) * NN + m0 + c) = v;
        }
    }
}

// ---------------------------------------------------------------------------
// Kernel 2 v5: coalesced DMA staging (round-0 style) + T3 minimal 2-phase
// double buffer.
// Round-1/2 post-mortem: direct per-lane loads scatter 64x16B over 16 rows
// per instruction -> request-rate-bound (hbm 0.7-0.9 TB/s, all pipes idle).
// Round-0's global_load_lds staging is fully coalesced but single-buffered
// (vmcnt(0) drain exposed every step). This version: K_STEP=32, two
// 12 KB buffers (24 KB LDS, 4 blocks/CU, grid 1024 fully resident);
// per step: issue next tile's 3 DMA -> compute current from other buffer
// -> one inline vmcnt(0) + raw s_barrier (T3 recipe, m230/m248).
// XOR chunk swizzle on DMA *source* + swizzled read offsets, LDS linear
// (both-sides rule, m201/m231). Epilogue: shuffle rowsum + direct global
// write (round-2 verified, no LDS).
// ---------------------------------------------------------------------------
#define BUFB 12288   // bytes per buffer: A 4 KB + B 8 KB

__global__ __launch_bounds__(256, 4) void gcn_kernel(const float* __restrict__ adj,
                                                     const unsigned short* __restrict__ Yt,
                                                     const float* __restrict__ bias,
                                                     float* __restrict__ out) {
    __shared__ char smem[2 * BUFB];

    const int tid  = threadIdx.x;
    const int lane = tid & 63;
    const int w    = tid >> 6;

    const int raw = blockIdx.x;
    const int bid = (raw & 7) * 128 + (raw >> 3);    // XCD-contiguous, bijective
    const int b   = bid >> 5;
    const int n0  = (bid & 31) * 32;

    const int lcol = lane & 15, q = lane >> 4;
    const int wm = (w & 1) * 16;                     // row half  (0 / 16)
    const int wn = (w >> 1) * 64;                    // col half  (0 / 64)

    // ---- DMA source/dest (source carries the XOR chunk swizzle) ----
    // A: 32 rows x 32 fp32 = 4 KB/step = 4 instrs (1/wave).
    //    slot s = w*64+lane: row rA = s>>3, chunk c = s&7 (16B chunks).
    const int rA = w * 8 + (lane >> 3);
    const int gA = (lane & 7) ^ (lane >> 3);         // c ^ (rA&7)
    const float* aSrc = adj + ((size_t)(b * NN + n0 + rA)) * NN + gA * 4;
    char* aDst = smem + w * 1024;                    // + buf*BUFB

    // B: 128 rows x 32 bf16 = 8 KB/step = 8 instrs (2/wave).
    //    slot s = (w*2+j)*64+lane: row o = s>>2, chunk c = s&3.
    const unsigned short* bSrc[2];
    char* bDst[2];
    #pragma unroll
    for (int j = 0; j < 2; ++j) {
        const int s = (w * 2 + j) * 64 + lane;
        const int o = s >> 2, c = s & 3;
        const int g = c ^ (o & 3);
        bSrc[j] = Yt + ((size_t)(b * FOUT + o)) * NN + g * 8;
        bDst[j] = smem + 4096 + (w * 2 + j) * 1024;
    }

    // ---- fragment read byte-offsets within a buffer (swizzle folded in) ----
    const int R = wm + lcol, keyA = R & 7;
    const int offA0 = (R * 8 + ((2 * q)     ^ keyA)) * 16;
    const int offA1 = (R * 8 + ((2 * q + 1) ^ keyA)) * 16;
    int offB[4];
    #pragma unroll
    for (int ni = 0; ni < 4; ++ni) {
        const int o = wn + ni * 16 + lcol;
        offB[ni] = 4096 + (o * 4 + (q ^ (o & 3))) * 16;
    }

    f32x4 acc[4] = {};
    float rsum = 0.f;

    #define STAGE(buf, s)                                                  \
        do {                                                               \
            load_lds16(aSrc    + (s) * 32, aDst    + (buf) * BUFB);        \
            load_lds16(bSrc[0] + (s) * 32, bDst[0] + (buf) * BUFB);        \
            load_lds16(bSrc[1] + (s) * 32, bDst[1] + (buf) * BUFB);        \
        } while (0)

    #define COMPUTE(buf)                                                   \
        do {                                                               \
            const char* base = smem + (buf) * BUFB;                        \
            const float4 f0 = *(const float4*)(base + offA0);              \
            const float4 f1 = *(const float4*)(base + offA1);              \
            rsum += ((f0.x + f0.y) + (f0.z + f0.w))                        \
                  + ((f1.x + f1.y) + (f1.z + f1.w));                       \
            uint4 pk;                                                      \
            pk.x = pack2(f0.x, f0.y); pk.y = pack2(f0.z, f0.w);            \
            pk.z = pack2(f1.x, f1.y); pk.w = pack2(f1.z, f1.w);            \
            const bf16x8 a = *(const bf16x8*)&pk;                          \
            _Pragma("unroll")                                              \
            for (int ni = 0; ni < 4; ++ni) {                               \
                const bf16x8 bbf = *(const bf16x8*)(base + offB[ni]);      \
                acc[ni] = __builtin_amdgcn_mfma_f32_16x16x32_bf16(         \
                    a, bbf, acc[ni], 0, 0, 0);                             \
            }                                                              \
        } while (0)

    // prologue: fill buf0 with step 0
    STAGE(0, 0);
    asm volatile("s_waitcnt vmcnt(0)" ::: "memory");
    __builtin_amdgcn_s_barrier();

    // 32 K-steps, unrolled x2 so buffer offsets are compile-time
    for (int t = 0; t < 16; ++t) {
        STAGE(1, 2 * t + 1);                 // next tile -> buf1 (flies under compute)
        COMPUTE(0);                          // step 2t from buf0
        asm volatile("s_waitcnt vmcnt(0)" ::: "memory");
        __builtin_amdgcn_s_barrier();

        if (t < 15) STAGE(0, 2 * t + 2);     // next tile -> buf0
        COMPUTE(1);                          // step 2t+1 from buf1
        asm volatile("s_waitcnt vmcnt(0)" ::: "memory");
        __builtin_amdgcn_s_barrier();
    }
    #undef STAGE
    #undef COMPUTE

    // full row sums: lanes sharing lcol hold disjoint k-slices of row wm+lcol
    rsum += __shfl_xor(rsum, 16);
    rsum += __shfl_xor(rsum, 32);

    // D layout: col = lane&15 (o), row-in-tile = q*4 + r.
    // 1/rowsum for row wm+(rq+r): lane rq+r holds it (lcol = rq+r).
    const int rq = q * 4;
    float sc[4];
    #pragma unroll
    for (int r = 0; r < 4; ++r) sc[r] = 1.0f / __shfl(rsum, rq + r);

    float* outB = out + ((size_t)(b * NN + n0 + wm)) * FOUT;
    #pragma unroll
    for (int ni = 0; ni < 4; ++ni) {
        const float bc = bias[wn + ni * 16 + lcol];
        #pragma unroll
        for (int r = 0; r < 4; ++r) {
            float v = acc[ni][r] * sc[r] + bc;
            v = (v >= 0.f) ? v : 0.01f * v;
            outB[(size_t)(rq + r) * FOUT + wn + ni * 16 + lcol] = v;
        }
    }
}

extern "C" void kernel_launch(void* const* d_in, const int* in_sizes, int n_in,
                              void* d_out, int out_size, void* d_ws, size_t ws_size,
                              hipStream_t stream) {
    const float* node = (const float*)d_in[0];   // [32,1024,128]
    const float* adj  = (const float*)d_in[1];   // [32,1024,1024]
    const float* W    = (const float*)d_in[2];   // [128,128]
    const float* bias = (const float*)d_in[3];   // [128]
    float* out = (float*)d_out;                  // [32,1024,128] fp32
    unsigned short* Yt = (unsigned short*)d_ws;  // [32,128,1024] bf16 = 8 MiB

    hipLaunchKernelGGL(y_kernel,   dim3(512),  dim3(256), 0, stream, node, W, Yt);
    hipLaunchKernelGGL(gcn_kernel, dim3(1024), dim3(256), 0, stream, adj, Yt, bias, out);
}